// Round 20
// baseline (558.024 us; speedup 1.0000x reference)
//
#include <hip/hip_runtime.h>
#include <hip/hip_bf16.h>
#include <math.h>

#define NF 128
#define EC 50
#define ET 64              // node-ownership window (off/tnlo granularity)
#define WT 128             // wf_kernel edges per MFMA tile
#define SCH 2048           // scan chunk size
#define CUTOFF 0.8f
#define PI_F 3.14159265358979323846f

typedef __attribute__((ext_vector_type(8))) _Float16 f16x8;
typedef __attribute__((ext_vector_type(2))) _Float16 f16x2;
typedef __attribute__((ext_vector_type(4))) float f32x4;

__device__ __forceinline__ float4 ld4(const float* p) { return *reinterpret_cast<const float4*>(p); }

// fast ssp: hardware exp/log; validated R7-R19 (absmax <= 0.0078)
__device__ __forceinline__ float sspf(float x) {
    return fmaxf(x, 0.0f) + __logf(1.0f + __expf(-fabsf(x))) - 0.69314718055994530942f;
}
__device__ __forceinline__ float swishf(float x) {
    return x / (1.0f + __expf(-x));
}

// -------------------------------------------------------------------------
// emb -> fp16 B2
__global__ __launch_bounds__(256) void emb_kernel(const float* __restrict__ tt,
                                                  _Float16* __restrict__ emb, int n) {
    int i = blockIdx.x * blockDim.x + threadIdx.x;
    if (i >= n * 64) return;
    int node = i >> 6, k = i & 63;
    float t = tt[node];
    float coef = __expf((float)k * (-6.9077552789821368f / 63.0f));
    float e = t * coef;
    emb[node * NF + k]      = (_Float16)swishf(__sinf(e));
    emb[node * NF + 64 + k] = (_Float16)swishf(__cosf(e));
}

// -------------------------------------------------------------------------
// MFMA node GEMM (R16-verified fragments): out = f(A @ W (+bias) (+extra)).
template<int MODE, int A16, int O16>
__global__ void mfma_gemm(const void* __restrict__ Av,
                          const float* __restrict__ W,
                          const float* __restrict__ bias,
                          const _Float16* extra,
                          void* outv, int n) {
    __shared__ __align__(16) char A_lds[64 * 256];   // [64 rows][128 k] fp16 swizzled
    const int tid  = threadIdx.x;
    const int wid  = tid >> 6;
    const int lane = tid & 63;
    const int l15  = lane & 15;
    const int lhi  = lane >> 4;

    f16x8 wfr[2][4];
    float bc[2];
    #pragma unroll
    for (int ct = 0; ct < 2; ct++) {
        const int col = (2 * wid + ct) * 16 + l15;
        bc[ct] = (MODE != 0) ? bias[col] : 0.0f;
        #pragma unroll
        for (int t = 0; t < 4; t++)
            #pragma unroll
            for (int j = 0; j < 8; j++) {
                int k = t * 32 + lhi * 8 + j;
                wfr[ct][t][j] = (_Float16)W[k * NF + col];
            }
    }

    const int ntile = (n + 63) >> 6;
    for (int tile = blockIdx.x; tile < ntile; tile += gridDim.x) {
        const int base = tile << 6;
        __syncthreads();
        {
            int row = tid >> 2, part = tid & 3;
            int grow = base + row;
            bool val = grow < n;
            if (A16) {
                const _Float16* ap = (const _Float16*)Av + (size_t)grow * NF + part * 32;
                #pragma unroll
                for (int kk = 0; kk < 32; kk += 8) {
                    uint4 v = val ? *(const uint4*)(ap + kk)
                                  : make_uint4(0u, 0u, 0u, 0u);
                    int k = part * 32 + kk;
                    *(unsigned*)(A_lds + row * 256 + ((2 * (k + 0)) ^ ((row & 7) << 4))) = v.x;
                    *(unsigned*)(A_lds + row * 256 + ((2 * (k + 2)) ^ ((row & 7) << 4))) = v.y;
                    *(unsigned*)(A_lds + row * 256 + ((2 * (k + 4)) ^ ((row & 7) << 4))) = v.z;
                    *(unsigned*)(A_lds + row * 256 + ((2 * (k + 6)) ^ ((row & 7) << 4))) = v.w;
                }
            } else {
                const float* ap = (const float*)Av + (size_t)grow * NF + part * 32;
                #pragma unroll
                for (int kk = 0; kk < 32; kk += 4) {
                    float4 v = val ? ld4(ap + kk) : make_float4(0.f, 0.f, 0.f, 0.f);
                    int k = part * 32 + kk;
                    f16x2 p0; p0[0] = (_Float16)v.x; p0[1] = (_Float16)v.y;
                    f16x2 p1; p1[0] = (_Float16)v.z; p1[1] = (_Float16)v.w;
                    *(f16x2*)(A_lds + row * 256 + ((2 * k)       ^ ((row & 7) << 4))) = p0;
                    *(f16x2*)(A_lds + row * 256 + ((2 * (k + 2)) ^ ((row & 7) << 4))) = p1;
                }
            }
        }
        __syncthreads();

        f32x4 acc[4][2];
        #pragma unroll
        for (int m = 0; m < 4; m++) {
            #pragma unroll
            for (int ct = 0; ct < 2; ct++) {
                f32x4 b = {bc[ct], bc[ct], bc[ct], bc[ct]};
                acc[m][ct] = b;
            }
            const int row = m * 16 + l15;
            #pragma unroll
            for (int t2 = 0; t2 < 4; t2++) {
                int o = row * 256 + ((t2 * 64 + lhi * 16) ^ ((row & 7) << 4));
                f16x8 a = *(const f16x8*)(A_lds + o);
                #pragma unroll
                for (int ct = 0; ct < 2; ct++)
                    acc[m][ct] = __builtin_amdgcn_mfma_f32_16x16x32_f16(a, wfr[ct][t2], acc[m][ct], 0, 0, 0);
            }
        }

        #pragma unroll
        for (int m = 0; m < 4; m++) {
            #pragma unroll
            for (int ct = 0; ct < 2; ct++) {
                const int col = (2 * wid + ct) * 16 + l15;
                #pragma unroll
                for (int r = 0; r < 4; r++) {
                    int grow = base + m * 16 + lhi * 4 + r;
                    if (grow >= n) continue;
                    float v = acc[m][ct][r];
                    if (MODE == 2) v += (float)extra[(size_t)grow * NF + col];
                    if (MODE == 1 || MODE == 2) v = sspf(v);
                    if (O16)
                        ((_Float16*)outv)[(size_t)grow * NF + col] = (_Float16)v;
                    else
                        ((float*)outv)[(size_t)grow * NF + col] = v;
                }
            }
        }
    }
}

// -------------------------------------------------------------------------
// CSR build: degree -> 3-phase multi-block exclusive scan -> scatter.
__global__ __launch_bounds__(256) void deg_kernel(const int* __restrict__ ei,
                                                  int* __restrict__ deg, int E_) {
    int e = blockIdx.x * blockDim.x + threadIdx.x;
    if (e < E_) atomicAdd(&deg[ei[E_ + e]], 1);
}

__global__ __launch_bounds__(256) void scan_chunk(const int* __restrict__ deg,
                                                  int* __restrict__ csum, int n) {
    int base = blockIdx.x * SCH;
    int s = 0;
    for (int i = threadIdx.x; i < SCH; i += 256) {
        int idx = base + i;
        if (idx < n) s += deg[idx];
    }
    __shared__ int red[4];
    #pragma unroll
    for (int d = 1; d < 64; d <<= 1) s += __shfl_xor(s, d);
    if ((threadIdx.x & 63) == 0) red[threadIdx.x >> 6] = s;
    __syncthreads();
    if (threadIdx.x == 0) csum[blockIdx.x] = red[0] + red[1] + red[2] + red[3];
}

__global__ __launch_bounds__(1024) void scan_csum_k(const int* __restrict__ csum,
                                                    int* __restrict__ coff, int nch,
                                                    int* __restrict__ off, int n, int E_) {
    __shared__ int sm[1024];
    const int tid = threadIdx.x;
    int v = (tid < nch) ? csum[tid] : 0;
    sm[tid] = v;
    __syncthreads();
    for (int st = 1; st < 1024; st <<= 1) {
        int t = (tid >= st) ? sm[tid - st] : 0;
        __syncthreads();
        sm[tid] += t;
        __syncthreads();
    }
    if (tid < nch) coff[tid] = sm[tid] - v;   // exclusive
    if (tid == 0) off[n] = E_;                // total degree == E
}

__global__ __launch_bounds__(256) void scan_emit(const int* __restrict__ deg,
                                                 const int* __restrict__ coff,
                                                 int* __restrict__ off, int n) {
    const int base = blockIdx.x * SCH + threadIdx.x * 8;
    int vals[8]; int s = 0;
    #pragma unroll
    for (int j = 0; j < 8; j++) {
        int idx = base + j;
        vals[j] = (idx < n) ? deg[idx] : 0;
        s += vals[j];
    }
    __shared__ int ts[256];
    ts[threadIdx.x] = s;
    __syncthreads();
    for (int st = 1; st < 256; st <<= 1) {
        int t = (threadIdx.x >= st) ? ts[threadIdx.x - st] : 0;
        __syncthreads();
        ts[threadIdx.x] += t;
        __syncthreads();
    }
    int prefix = coff[blockIdx.x] + ts[threadIdx.x] - s;
    #pragma unroll
    for (int j = 0; j < 8; j++) {
        int idx = base + j;
        if (idx < n) off[idx] = prefix;
        prefix += vals[j];
    }
}

__global__ __launch_bounds__(256) void scatter_kernel(const int* __restrict__ ei,
                                                      const float* __restrict__ elen,
                                                      const int* __restrict__ off,
                                                      int* __restrict__ cur,
                                                      int* __restrict__ perm,
                                                      int* __restrict__ srcp,
                                                      float* __restrict__ Cp, int E_) {
    int e = blockIdx.x * blockDim.x + threadIdx.x;
    if (e < E_) {
        int d = ei[E_ + e];
        int p = off[d] + atomicAdd(&cur[d], 1);
        perm[p] = e;
        srcp[p] = ei[e];
        float len = elen[e];
        float c = 0.5f * (__cosf(len * (PI_F / CUTOFF)) + 1.0f);
        Cp[p] = (len <= CUTOFF && len >= 0.0f) ? c : 0.0f;
    }
}

// tnlo[t] = first node n with off[n] >= 64*t (tile ownership table)
__global__ __launch_bounds__(256) void tilebnd_kernel(const int* __restrict__ off,
                                                      int* __restrict__ tnlo,
                                                      int nN, int ntiles) {
    int t = blockIdx.x * blockDim.x + threadIdx.x;
    if (t > ntiles) return;
    if (t == ntiles) { tnlo[t] = nN; return; }
    int key = t * ET;
    int lo = 0, hi = nN + 1;
    while (lo < hi) { int mid = (lo + hi) >> 1; if (off[mid] < key) lo = mid + 1; else hi = mid; }
    tnlo[t] = lo;
}

// -------------------------------------------------------------------------
// wf_kernel — WT=128-edge tiles, 512 thr / 8 waves, one 16-col tile/wave,
// with T14 async-stage: next tile's perm/eattr/Cp loaded into REGISTERS
// during layer2/msg/copy of the current tile; staging at loop top is a pure
// reg->LDS write (zero exposed gather latency). +9 VGPR (73 < cap 128).
__global__ __launch_bounds__(512, 4) void wf_kernel(const float* __restrict__ eattr,
                                                    const float* __restrict__ em1w,
                                                    const float* __restrict__ em1b,
                                                    const float* __restrict__ em2w,
                                                    const float* __restrict__ em2b,
                                                    const int* __restrict__ perm,
                                                    const float* __restrict__ Cp,
                                                    unsigned int* __restrict__ wmsg32,
                                                    int E_) {
    __shared__ __align__(16) char U[WT * 128 + WT * 256];   // ea 16K | h 32K
    __shared__ float C_sm[WT];
    char* ea_p  = U;               // [128][64k] fp16 swizzled
    char* h_p   = U + WT * 128;    // [128][128ch] fp16 swizzled
    char* msg_b = U;               // [128] rows x 264B (33.8K), overlays ea/h

    const int tid  = threadIdx.x;
    const int wid  = tid >> 6;     // wave 0..7 -> column tile (16 ch)
    const int lane = tid & 63;
    const int l15  = lane & 15;
    const int lhi  = lane >> 4;
    const int col  = wid * 16 + l15;
    const int row  = tid >> 2;     // staging row (0..127)
    const int part = tid & 3;      // staging k-quarter

    f16x8 w1f[2];
    f16x8 w2f[4];
    const float b1c = em1b[col];
    const float b2c = em2b[col];
    #pragma unroll
    for (int t = 0; t < 2; t++)
        #pragma unroll
        for (int j = 0; j < 8; j++) {
            int k = t * 32 + lhi * 8 + j;
            w1f[t][j] = (_Float16)((k < EC) ? em1w[k * NF + col] : 0.0f);
        }
    #pragma unroll
    for (int t = 0; t < 4; t++)
        #pragma unroll
        for (int j = 0; j < 8; j++) {
            int k = t * 32 + lhi * 8 + j;
            w2f[t][j] = (_Float16)em2w[k * NF + col];
        }

    const int ntiles = (E_ + WT - 1) / WT;

    // ---- prologue: prefetch first tile into registers
    unsigned int pea[8];
    float cpre;
    {
        const int pt = blockIdx.x;
        const int pbase = pt * WT;
        const bool tv = pt < ntiles;
        const int pec = tv ? min(WT, E_ - pbase) : 0;
        const bool val = row < pec;
        const float* ep = eattr + (size_t)(val ? perm[pbase + row] : 0) * EC;
        #pragma unroll
        for (int kk = 0; kk < 16; kk += 2) {
            int k = part * 16 + kk;
            float2 v = make_float2(0.f, 0.f);
            if (val && k <= 48) v = *(const float2*)(ep + k);
            f16x2 q; q[0] = (_Float16)v.x; q[1] = (_Float16)v.y;
            pea[kk >> 1] = *(const unsigned int*)&q;
        }
        cpre = (tid < pec) ? Cp[pbase + tid] : 0.0f;
    }

    for (int tile = blockIdx.x; tile < ntiles; tile += gridDim.x) {
        const int base = tile * WT;
        const int ec = min(WT, E_ - base);
        const int mmax = (ec + 15) >> 4;     // up to 8
        __syncthreads();   // prev msg copy done; ea/msg region free

        // ---- stage from registers (no global latency on critical path)
        if (tid < WT) C_sm[tid] = cpre;
        #pragma unroll
        for (int kk = 0; kk < 16; kk += 2) {
            int k = part * 16 + kk;
            *(unsigned int*)(ea_p + row * 128 + ((2 * k) ^ ((row & 7) << 4))) = pea[kk >> 1];
        }
        __syncthreads();

        // layer 1: h = ssp(ea @ em1 + b1), 8 m-tiles
        f32x4 acc[8];
        #pragma unroll
        for (int m = 0; m < 8; m++) {
            if (m < mmax) {
                f32x4 b = {b1c, b1c, b1c, b1c};
                acc[m] = b;
                const int rw = m * 16 + l15;
                #pragma unroll
                for (int t1 = 0; t1 < 2; t1++) {
                    int o = rw * 128 + ((t1 * 64 + lhi * 16) ^ ((rw & 7) << 4));
                    f16x8 a = *(const f16x8*)(ea_p + o);
                    acc[m] = __builtin_amdgcn_mfma_f32_16x16x32_f16(a, w1f[t1], acc[m], 0, 0, 0);
                }
            }
        }
        #pragma unroll
        for (int m = 0; m < 8; m++) {
            if (m < mmax) {
                #pragma unroll
                for (int r = 0; r < 4; r++) {
                    int rw = m * 16 + lhi * 4 + r;
                    *(_Float16*)(h_p + rw * 256 + ((2 * col) ^ ((rw & 7) << 4))) =
                        (_Float16)sspf(acc[m][r]);
                }
            }
        }

        // ---- prefetch NEXT tile into regs (hides under layer2/msg/copy)
        {
            const int pt = tile + gridDim.x;
            const int pbase = pt * WT;
            const bool tv = pt < ntiles;
            const int pec = tv ? min(WT, E_ - pbase) : 0;
            const bool val = row < pec;
            const float* ep = eattr + (size_t)(val ? perm[pbase + row] : 0) * EC;
            #pragma unroll
            for (int kk = 0; kk < 16; kk += 2) {
                int k = part * 16 + kk;
                float2 v = make_float2(0.f, 0.f);
                if (val && k <= 48) v = *(const float2*)(ep + k);
                f16x2 q; q[0] = (_Float16)v.x; q[1] = (_Float16)v.y;
                pea[kk >> 1] = *(const unsigned int*)&q;
            }
            cpre = (tid < pec) ? Cp[pbase + tid] : 0.0f;
        }
        __syncthreads();

        // layer 2: wf = h @ em2 + b2
        #pragma unroll
        for (int m = 0; m < 8; m++) {
            if (m < mmax) {
                f32x4 b = {b2c, b2c, b2c, b2c};
                acc[m] = b;
                const int rw = m * 16 + l15;
                #pragma unroll
                for (int t2 = 0; t2 < 4; t2++) {
                    int o = rw * 256 + ((t2 * 64 + lhi * 16) ^ ((rw & 7) << 4));
                    f16x8 a = *(const f16x8*)(h_p + o);
                    acc[m] = __builtin_amdgcn_mfma_f32_16x16x32_f16(a, w2f[t2], acc[m], 0, 0, 0);
                }
            }
        }
        __syncthreads();   // h reads done; msg overlays ea/h

        #pragma unroll
        for (int m = 0; m < 8; m++) {
            if (m < mmax) {
                #pragma unroll
                for (int r = 0; r < 4; r++) {
                    int e = m * 16 + lhi * 4 + r;
                    *(_Float16*)(msg_b + e * 264 + 2 * col) =
                        (_Float16)(acc[m][r] * C_sm[e]);
                }
            }
        }
        __syncthreads();

        // coalesced LDS -> global copy (non-temporal stream)
        for (int j = tid; j < ec * 64; j += 512)
            __builtin_nontemporal_store(
                *(const unsigned int*)(msg_b + (j >> 6) * 264 + (j & 63) * 4),
                &wmsg32[(size_t)base * 64 + j]);
    }
}

// -------------------------------------------------------------------------
// red_conv — pure gather-reduce; fp16 y rows (256B), fp16 agg (R18-verified).
__global__ __launch_bounds__(256) void red_conv(const unsigned int* __restrict__ y32,
                                                const unsigned int* __restrict__ wmsg32,
                                                const int* __restrict__ srcp,
                                                const int* __restrict__ off,
                                                const int* __restrict__ tnlo,
                                                unsigned int* __restrict__ agg32,
                                                int ntiles) {
    const int wid  = threadIdx.x >> 6;
    const int lane = threadIdx.x & 63;

    for (int tile = blockIdx.x; tile < ntiles; tile += gridDim.x) {
        const int n_lo = tnlo[tile], n_hi1 = tnlo[tile + 1];
        for (int n = n_lo + wid; n < n_hi1; n += 4) {
            float2 a = make_float2(0.f, 0.f);
            int i = off[n];
            const int e1 = off[n + 1];
            for (; i + 4 <= e1; i += 4) {
                int s0 = srcp[i], s1 = srcp[i + 1], s2 = srcp[i + 2], s3 = srcp[i + 3];
                unsigned int u0 = __builtin_nontemporal_load(&wmsg32[(size_t)(i    ) * 64 + lane]);
                unsigned int u1 = __builtin_nontemporal_load(&wmsg32[(size_t)(i + 1) * 64 + lane]);
                unsigned int u2 = __builtin_nontemporal_load(&wmsg32[(size_t)(i + 2) * 64 + lane]);
                unsigned int u3 = __builtin_nontemporal_load(&wmsg32[(size_t)(i + 3) * 64 + lane]);
                unsigned int v0 = y32[(size_t)s0 * 64 + lane];
                unsigned int v1 = y32[(size_t)s1 * 64 + lane];
                unsigned int v2 = y32[(size_t)s2 * 64 + lane];
                unsigned int v3 = y32[(size_t)s3 * 64 + lane];
                f16x2 m0 = *(const f16x2*)&u0, m1 = *(const f16x2*)&u1;
                f16x2 m2 = *(const f16x2*)&u2, m3 = *(const f16x2*)&u3;
                f16x2 q0 = *(const f16x2*)&v0, q1 = *(const f16x2*)&v1;
                f16x2 q2 = *(const f16x2*)&v2, q3 = *(const f16x2*)&v3;
                a.x = fmaf((float)m0[0], (float)q0[0], a.x); a.y = fmaf((float)m0[1], (float)q0[1], a.y);
                a.x = fmaf((float)m1[0], (float)q1[0], a.x); a.y = fmaf((float)m1[1], (float)q1[1], a.y);
                a.x = fmaf((float)m2[0], (float)q2[0], a.x); a.y = fmaf((float)m2[1], (float)q2[1], a.y);
                a.x = fmaf((float)m3[0], (float)q3[0], a.x); a.y = fmaf((float)m3[1], (float)q3[1], a.y);
            }
            for (; i < e1; i++) {
                unsigned int u = __builtin_nontemporal_load(&wmsg32[(size_t)i * 64 + lane]);
                unsigned int v = y32[(size_t)srcp[i] * 64 + lane];
                f16x2 mp = *(const f16x2*)&u;
                f16x2 qv = *(const f16x2*)&v;
                a.x = fmaf((float)mp[0], (float)qv[0], a.x);
                a.y = fmaf((float)mp[1], (float)qv[1], a.y);
            }
            f16x2 o; o[0] = (_Float16)a.x; o[1] = (_Float16)a.y;
            agg32[(size_t)n * 64 + lane] = *(const unsigned int*)&o;
        }
    }
}

// -------------------------------------------------------------------------
extern "C" void kernel_launch(void* const* d_in, const int* in_sizes, int n_in,
                              void* d_out, int out_size, void* d_ws, size_t ws_size,
                              hipStream_t stream) {
    const float* tt    = (const float*)d_in[0];
    const float* xx    = (const float*)d_in[1];
    const int*   ei    = (const int*)d_in[2];
    const float* elen  = (const float*)d_in[3];
    const float* eattr = (const float*)d_in[4];
    const float* em1w  = (const float*)d_in[5];
    const float* em1b  = (const float*)d_in[6];
    const float* em2w  = (const float*)d_in[7];
    const float* em2b  = (const float*)d_in[8];
    const float* c1m1w = (const float*)d_in[9];
    const float* c1m2w = (const float*)d_in[10];
    const float* c1m2b = (const float*)d_in[11];
    const float* c2m1w = (const float*)d_in[12];
    const float* c2m2w = (const float*)d_in[13];
    const float* c2m2b = (const float*)d_in[14];
    const float* tew   = (const float*)d_in[15];
    const float* teb   = (const float*)d_in[16];
    const float* linw  = (const float*)d_in[17];
    const float* linb  = (const float*)d_in[18];

    const int n  = in_sizes[0];
    const int E_ = in_sizes[2] / 2;
    const int ntiles = (E_ + ET - 1) / ET;
    const int gtiles = (n + 63) >> 6;
    const int nch = (n + SCH - 1) / SCH;
    float* out = (float*)d_out;

    // ws layout: fp16 node buffers (3 x NB halfs) then CSR ints + wmsg.
    const size_t NB = (size_t)n * NF;
    _Float16* B0h = (_Float16*)d_ws;   // y1 / y2 / x3   (fp16)
    _Float16* B1h = B0h + NB;          // agg            (fp16)
    _Float16* B2h = B1h + NB;          // emb/t/x_mid    (fp16)
    int* off  = (int*)(B2h + NB);      // n+1
    int* perm = off + (n + 1);         // E
    int* deg  = perm + E_;             // n
    int* cur  = deg + n;               // n
    int* srcp = cur + n;               // E
    int* tnlo = srcp + E_;             // ntiles+1
    int* csum = tnlo + ntiles + 1;     // nch
    int* coff = csum + nch;            // nch
    float* Cp = (float*)(coff + nch);  // E
    unsigned int* wmsg32 = (unsigned int*)(Cp + E_);   // E*64 u32

    // ---- CSR build (multi-block scan) + ownership table
    hipMemsetAsync(deg, 0, (size_t)2 * n * sizeof(int), stream);
    deg_kernel<<<(E_ + 255) / 256, 256, 0, stream>>>(ei, deg, E_);
    scan_chunk<<<nch, 256, 0, stream>>>(deg, csum, n);
    scan_csum_k<<<1, 1024, 0, stream>>>(csum, coff, nch, off, n, E_);
    scan_emit<<<nch, 256, 0, stream>>>(deg, coff, off, n);
    scatter_kernel<<<(E_ + 255) / 256, 256, 0, stream>>>(ei, elen, off, cur,
                                                         perm, srcp, Cp, E_);
    tilebnd_kernel<<<(ntiles + 256) / 256, 256, 0, stream>>>(off, tnlo, n, ntiles);

    // emb -> B2h ; t = swish_emb @ te_w + te_b -> B2h (in-place safe)
    emb_kernel<<<(n * 64 + 255) / 256, 256, 0, stream>>>(tt, B2h, n);
    mfma_gemm<3, 1, 1><<<gtiles, 256, 0, stream>>>(B2h, tew, teb, nullptr, B2h, n);

    // msg = Wf*C (conv-invariant) computed ONCE; WT=128 tiles, reg-prefetch
    wf_kernel<<<1280, 512, 0, stream>>>(eattr, em1w, em1b, em2w, em2b,
                                        perm, Cp, wmsg32, E_);

    // y1 = xx @ c1_m1w -> B0h   (A = f32 input)
    mfma_gemm<0, 0, 1><<<gtiles, 256, 0, stream>>>(xx, c1m1w, nullptr, nullptr, B0h, n);

    // conv1 -> B1h
    red_conv<<<4096, 256, 0, stream>>>((const unsigned int*)B0h, wmsg32, srcp,
                                       off, tnlo, (unsigned int*)B1h, ntiles);

    // x_mid = ssp(agg @ c1_m2w + b + t) -> B2h (extra==out elementwise-safe)
    mfma_gemm<2, 1, 1><<<gtiles, 256, 0, stream>>>(B1h, c1m2w, c1m2b, B2h, B2h, n);

    // y2 = x_mid @ c2_m1w -> B0h
    mfma_gemm<0, 1, 1><<<gtiles, 256, 0, stream>>>(B2h, c2m1w, nullptr, nullptr, B0h, n);

    // conv2 -> B1h
    red_conv<<<4096, 256, 0, stream>>>((const unsigned int*)B0h, wmsg32, srcp,
                                       off, tnlo, (unsigned int*)B1h, ntiles);

    // x3 = ssp(agg @ c2_m2w + b) -> B0h ; out = ssp(x3 @ lin_w + b) -> d_out (f32)
    mfma_gemm<1, 1, 1><<<gtiles, 256, 0, stream>>>(B1h, c2m2w, c2m2b, nullptr, B0h, n);
    mfma_gemm<1, 1, 0><<<gtiles, 256, 0, stream>>>(B0h, linw, linb, nullptr, out, n);
}

// Round 21
// 532.517 us; speedup vs baseline: 1.0479x; 1.0479x over previous
//
#include <hip/hip_runtime.h>
#include <hip/hip_bf16.h>
#include <math.h>

#define NF 128
#define EC 50
#define ET 64              // node-ownership window (off/tnlo granularity)
#define WT 128             // wf_kernel edges per MFMA tile
#define SCH 2048           // scan chunk size
#define CUTOFF 0.8f
#define PI_F 3.14159265358979323846f

typedef __attribute__((ext_vector_type(8))) _Float16 f16x8;
typedef __attribute__((ext_vector_type(2))) _Float16 f16x2;
typedef __attribute__((ext_vector_type(4))) float f32x4;

__device__ __forceinline__ float4 ld4(const float* p) { return *reinterpret_cast<const float4*>(p); }

// fast ssp: hardware exp/log; validated R7-R19 (absmax <= 0.0078)
__device__ __forceinline__ float sspf(float x) {
    return fmaxf(x, 0.0f) + __logf(1.0f + __expf(-fabsf(x))) - 0.69314718055994530942f;
}
__device__ __forceinline__ float swishf(float x) {
    return x / (1.0f + __expf(-x));
}

// -------------------------------------------------------------------------
// emb -> fp16 B2
__global__ __launch_bounds__(256) void emb_kernel(const float* __restrict__ tt,
                                                  _Float16* __restrict__ emb, int n) {
    int i = blockIdx.x * blockDim.x + threadIdx.x;
    if (i >= n * 64) return;
    int node = i >> 6, k = i & 63;
    float t = tt[node];
    float coef = __expf((float)k * (-6.9077552789821368f / 63.0f));
    float e = t * coef;
    emb[node * NF + k]      = (_Float16)swishf(__sinf(e));
    emb[node * NF + 64 + k] = (_Float16)swishf(__cosf(e));
}

// -------------------------------------------------------------------------
// MFMA node GEMM (R16-verified fragments): out = f(A @ W (+bias) (+extra)).
template<int MODE, int A16, int O16>
__global__ void mfma_gemm(const void* __restrict__ Av,
                          const float* __restrict__ W,
                          const float* __restrict__ bias,
                          const _Float16* extra,
                          void* outv, int n) {
    __shared__ __align__(16) char A_lds[64 * 256];   // [64 rows][128 k] fp16 swizzled
    const int tid  = threadIdx.x;
    const int wid  = tid >> 6;
    const int lane = tid & 63;
    const int l15  = lane & 15;
    const int lhi  = lane >> 4;

    f16x8 wfr[2][4];
    float bc[2];
    #pragma unroll
    for (int ct = 0; ct < 2; ct++) {
        const int col = (2 * wid + ct) * 16 + l15;
        bc[ct] = (MODE != 0) ? bias[col] : 0.0f;
        #pragma unroll
        for (int t = 0; t < 4; t++)
            #pragma unroll
            for (int j = 0; j < 8; j++) {
                int k = t * 32 + lhi * 8 + j;
                wfr[ct][t][j] = (_Float16)W[k * NF + col];
            }
    }

    const int ntile = (n + 63) >> 6;
    for (int tile = blockIdx.x; tile < ntile; tile += gridDim.x) {
        const int base = tile << 6;
        __syncthreads();
        {
            int row = tid >> 2, part = tid & 3;
            int grow = base + row;
            bool val = grow < n;
            if (A16) {
                const _Float16* ap = (const _Float16*)Av + (size_t)grow * NF + part * 32;
                #pragma unroll
                for (int kk = 0; kk < 32; kk += 8) {
                    uint4 v = val ? *(const uint4*)(ap + kk)
                                  : make_uint4(0u, 0u, 0u, 0u);
                    int k = part * 32 + kk;
                    *(unsigned*)(A_lds + row * 256 + ((2 * (k + 0)) ^ ((row & 7) << 4))) = v.x;
                    *(unsigned*)(A_lds + row * 256 + ((2 * (k + 2)) ^ ((row & 7) << 4))) = v.y;
                    *(unsigned*)(A_lds + row * 256 + ((2 * (k + 4)) ^ ((row & 7) << 4))) = v.z;
                    *(unsigned*)(A_lds + row * 256 + ((2 * (k + 6)) ^ ((row & 7) << 4))) = v.w;
                }
            } else {
                const float* ap = (const float*)Av + (size_t)grow * NF + part * 32;
                #pragma unroll
                for (int kk = 0; kk < 32; kk += 4) {
                    float4 v = val ? ld4(ap + kk) : make_float4(0.f, 0.f, 0.f, 0.f);
                    int k = part * 32 + kk;
                    f16x2 p0; p0[0] = (_Float16)v.x; p0[1] = (_Float16)v.y;
                    f16x2 p1; p1[0] = (_Float16)v.z; p1[1] = (_Float16)v.w;
                    *(f16x2*)(A_lds + row * 256 + ((2 * k)       ^ ((row & 7) << 4))) = p0;
                    *(f16x2*)(A_lds + row * 256 + ((2 * (k + 2)) ^ ((row & 7) << 4))) = p1;
                }
            }
        }
        __syncthreads();

        f32x4 acc[4][2];
        #pragma unroll
        for (int m = 0; m < 4; m++) {
            #pragma unroll
            for (int ct = 0; ct < 2; ct++) {
                f32x4 b = {bc[ct], bc[ct], bc[ct], bc[ct]};
                acc[m][ct] = b;
            }
            const int row = m * 16 + l15;
            #pragma unroll
            for (int t2 = 0; t2 < 4; t2++) {
                int o = row * 256 + ((t2 * 64 + lhi * 16) ^ ((row & 7) << 4));
                f16x8 a = *(const f16x8*)(A_lds + o);
                #pragma unroll
                for (int ct = 0; ct < 2; ct++)
                    acc[m][ct] = __builtin_amdgcn_mfma_f32_16x16x32_f16(a, wfr[ct][t2], acc[m][ct], 0, 0, 0);
            }
        }

        #pragma unroll
        for (int m = 0; m < 4; m++) {
            #pragma unroll
            for (int ct = 0; ct < 2; ct++) {
                const int col = (2 * wid + ct) * 16 + l15;
                #pragma unroll
                for (int r = 0; r < 4; r++) {
                    int grow = base + m * 16 + lhi * 4 + r;
                    if (grow >= n) continue;
                    float v = acc[m][ct][r];
                    if (MODE == 2) v += (float)extra[(size_t)grow * NF + col];
                    if (MODE == 1 || MODE == 2) v = sspf(v);
                    if (O16)
                        ((_Float16*)outv)[(size_t)grow * NF + col] = (_Float16)v;
                    else
                        ((float*)outv)[(size_t)grow * NF + col] = v;
                }
            }
        }
    }
}

// -------------------------------------------------------------------------
// CSR build: degree -> 3-phase multi-block exclusive scan -> scatter.
__global__ __launch_bounds__(256) void deg_kernel(const int* __restrict__ ei,
                                                  int* __restrict__ deg, int E_) {
    int e = blockIdx.x * blockDim.x + threadIdx.x;
    if (e < E_) atomicAdd(&deg[ei[E_ + e]], 1);
}

__global__ __launch_bounds__(256) void scan_chunk(const int* __restrict__ deg,
                                                  int* __restrict__ csum, int n) {
    int base = blockIdx.x * SCH;
    int s = 0;
    for (int i = threadIdx.x; i < SCH; i += 256) {
        int idx = base + i;
        if (idx < n) s += deg[idx];
    }
    __shared__ int red[4];
    #pragma unroll
    for (int d = 1; d < 64; d <<= 1) s += __shfl_xor(s, d);
    if ((threadIdx.x & 63) == 0) red[threadIdx.x >> 6] = s;
    __syncthreads();
    if (threadIdx.x == 0) csum[blockIdx.x] = red[0] + red[1] + red[2] + red[3];
}

__global__ __launch_bounds__(1024) void scan_csum_k(const int* __restrict__ csum,
                                                    int* __restrict__ coff, int nch,
                                                    int* __restrict__ off, int n, int E_) {
    __shared__ int sm[1024];
    const int tid = threadIdx.x;
    int v = (tid < nch) ? csum[tid] : 0;
    sm[tid] = v;
    __syncthreads();
    for (int st = 1; st < 1024; st <<= 1) {
        int t = (tid >= st) ? sm[tid - st] : 0;
        __syncthreads();
        sm[tid] += t;
        __syncthreads();
    }
    if (tid < nch) coff[tid] = sm[tid] - v;   // exclusive
    if (tid == 0) off[n] = E_;                // total degree == E
}

__global__ __launch_bounds__(256) void scan_emit(const int* __restrict__ deg,
                                                 const int* __restrict__ coff,
                                                 int* __restrict__ off, int n) {
    const int base = blockIdx.x * SCH + threadIdx.x * 8;
    int vals[8]; int s = 0;
    #pragma unroll
    for (int j = 0; j < 8; j++) {
        int idx = base + j;
        vals[j] = (idx < n) ? deg[idx] : 0;
        s += vals[j];
    }
    __shared__ int ts[256];
    ts[threadIdx.x] = s;
    __syncthreads();
    for (int st = 1; st < 256; st <<= 1) {
        int t = (threadIdx.x >= st) ? ts[threadIdx.x - st] : 0;
        __syncthreads();
        ts[threadIdx.x] += t;
        __syncthreads();
    }
    int prefix = coff[blockIdx.x] + ts[threadIdx.x] - s;
    #pragma unroll
    for (int j = 0; j < 8; j++) {
        int idx = base + j;
        if (idx < n) off[idx] = prefix;
        prefix += vals[j];
    }
}

__global__ __launch_bounds__(256) void scatter_kernel(const int* __restrict__ ei,
                                                      const float* __restrict__ elen,
                                                      const int* __restrict__ off,
                                                      int* __restrict__ cur,
                                                      int* __restrict__ perm,
                                                      int* __restrict__ srcp,
                                                      float* __restrict__ Cp, int E_) {
    int e = blockIdx.x * blockDim.x + threadIdx.x;
    if (e < E_) {
        int d = ei[E_ + e];
        int p = off[d] + atomicAdd(&cur[d], 1);
        perm[p] = e;
        srcp[p] = ei[e];
        float len = elen[e];
        float c = 0.5f * (__cosf(len * (PI_F / CUTOFF)) + 1.0f);
        Cp[p] = (len <= CUTOFF && len >= 0.0f) ? c : 0.0f;
    }
}

// tnlo[t] = first node n with off[n] >= 64*t (tile ownership table)
__global__ __launch_bounds__(256) void tilebnd_kernel(const int* __restrict__ off,
                                                      int* __restrict__ tnlo,
                                                      int nN, int ntiles) {
    int t = blockIdx.x * blockDim.x + threadIdx.x;
    if (t > ntiles) return;
    if (t == ntiles) { tnlo[t] = nN; return; }
    int key = t * ET;
    int lo = 0, hi = nN + 1;
    while (lo < hi) { int mid = (lo + hi) >> 1; if (off[mid] < key) lo = mid + 1; else hi = mid; }
    tnlo[t] = lo;
}

// -------------------------------------------------------------------------
// wf_kernel — WT=128-edge tiles, 512 threads / 8 waves, one 16-col ct-tile
// per wave, 8 m-tiles per wave. (R19-verified; R20's register prefetch
// REGRESSED — compiler's implicit wave overlap already covers the gather.)
__global__ __launch_bounds__(512, 4) void wf_kernel(const float* __restrict__ eattr,
                                                    const float* __restrict__ em1w,
                                                    const float* __restrict__ em1b,
                                                    const float* __restrict__ em2w,
                                                    const float* __restrict__ em2b,
                                                    const int* __restrict__ perm,
                                                    const float* __restrict__ Cp,
                                                    unsigned int* __restrict__ wmsg32,
                                                    int E_) {
    __shared__ __align__(16) char U[WT * 128 + WT * 256];   // ea 16K | h 32K
    __shared__ float C_sm[WT];
    char* ea_p  = U;               // [128][64k] fp16 swizzled
    char* h_p   = U + WT * 128;    // [128][128ch] fp16 swizzled
    char* msg_b = U;               // [128] rows x 264B (33.8K), overlays ea/h

    const int tid  = threadIdx.x;
    const int wid  = tid >> 6;     // wave 0..7 -> column tile (16 ch)
    const int lane = tid & 63;
    const int l15  = lane & 15;
    const int lhi  = lane >> 4;
    const int col  = wid * 16 + l15;

    f16x8 w1f[2];
    f16x8 w2f[4];
    const float b1c = em1b[col];
    const float b2c = em2b[col];
    #pragma unroll
    for (int t = 0; t < 2; t++)
        #pragma unroll
        for (int j = 0; j < 8; j++) {
            int k = t * 32 + lhi * 8 + j;
            w1f[t][j] = (_Float16)((k < EC) ? em1w[k * NF + col] : 0.0f);
        }
    #pragma unroll
    for (int t = 0; t < 4; t++)
        #pragma unroll
        for (int j = 0; j < 8; j++) {
            int k = t * 32 + lhi * 8 + j;
            w2f[t][j] = (_Float16)em2w[k * NF + col];
        }

    const int ntiles = (E_ + WT - 1) / WT;
    for (int tile = blockIdx.x; tile < ntiles; tile += gridDim.x) {
        const int base = tile * WT;
        const int ec = min(WT, E_ - base);
        const int mmax = (ec + 15) >> 4;     // up to 8
        __syncthreads();   // prev copy done

        if (tid < WT) C_sm[tid] = (tid < ec) ? Cp[base + tid] : 0.0f;
        // stage ea: row = tid>>2 (0..127), part = tid&3, 16 k's (8 f16x2)
        {
            int row = tid >> 2, part = tid & 3;
            bool val = row < ec;
            const float* ep = eattr + (size_t)(val ? perm[base + row] : 0) * EC;
            #pragma unroll
            for (int kk = 0; kk < 16; kk += 2) {
                int k = part * 16 + kk;
                float2 v = make_float2(0.f, 0.f);
                if (val && k <= 48) v = *(const float2*)(ep + k);
                f16x2 pk;
                pk[0] = (_Float16)v.x; pk[1] = (_Float16)v.y;
                *(f16x2*)(ea_p + row * 128 + ((2 * k) ^ ((row & 7) << 4))) = pk;
            }
        }
        __syncthreads();

        // layer 1: h = ssp(ea @ em1 + b1), 8 m-tiles
        f32x4 acc[8];
        #pragma unroll
        for (int m = 0; m < 8; m++) {
            if (m < mmax) {
                f32x4 b = {b1c, b1c, b1c, b1c};
                acc[m] = b;
                const int row = m * 16 + l15;
                #pragma unroll
                for (int t1 = 0; t1 < 2; t1++) {
                    int o = row * 128 + ((t1 * 64 + lhi * 16) ^ ((row & 7) << 4));
                    f16x8 a = *(const f16x8*)(ea_p + o);
                    acc[m] = __builtin_amdgcn_mfma_f32_16x16x32_f16(a, w1f[t1], acc[m], 0, 0, 0);
                }
            }
        }
        #pragma unroll
        for (int m = 0; m < 8; m++) {
            if (m < mmax) {
                #pragma unroll
                for (int r = 0; r < 4; r++) {
                    int row = m * 16 + lhi * 4 + r;
                    *(_Float16*)(h_p + row * 256 + ((2 * col) ^ ((row & 7) << 4))) =
                        (_Float16)sspf(acc[m][r]);
                }
            }
        }
        __syncthreads();

        // layer 2: wf = h @ em2 + b2
        #pragma unroll
        for (int m = 0; m < 8; m++) {
            if (m < mmax) {
                f32x4 b = {b2c, b2c, b2c, b2c};
                acc[m] = b;
                const int row = m * 16 + l15;
                #pragma unroll
                for (int t2 = 0; t2 < 4; t2++) {
                    int o = row * 256 + ((t2 * 64 + lhi * 16) ^ ((row & 7) << 4));
                    f16x8 a = *(const f16x8*)(h_p + o);
                    acc[m] = __builtin_amdgcn_mfma_f32_16x16x32_f16(a, w2f[t2], acc[m], 0, 0, 0);
                }
            }
        }
        __syncthreads();   // h reads done; msg overlays ea/h

        #pragma unroll
        for (int m = 0; m < 8; m++) {
            if (m < mmax) {
                #pragma unroll
                for (int r = 0; r < 4; r++) {
                    int e = m * 16 + lhi * 4 + r;
                    *(_Float16*)(msg_b + e * 264 + 2 * col) =
                        (_Float16)(acc[m][r] * C_sm[e]);
                }
            }
        }
        __syncthreads();

        // coalesced LDS -> global copy (non-temporal stream)
        for (int j = tid; j < ec * 64; j += 512)
            __builtin_nontemporal_store(
                *(const unsigned int*)(msg_b + (j >> 6) * 264 + (j & 63) * 4),
                &wmsg32[(size_t)base * 64 + j]);
    }
}

// -------------------------------------------------------------------------
// red_conv — pure gather-reduce; fp16 y rows (256B), fp16 agg (R18-verified).
__global__ __launch_bounds__(256) void red_conv(const unsigned int* __restrict__ y32,
                                                const unsigned int* __restrict__ wmsg32,
                                                const int* __restrict__ srcp,
                                                const int* __restrict__ off,
                                                const int* __restrict__ tnlo,
                                                unsigned int* __restrict__ agg32,
                                                int ntiles) {
    const int wid  = threadIdx.x >> 6;
    const int lane = threadIdx.x & 63;

    for (int tile = blockIdx.x; tile < ntiles; tile += gridDim.x) {
        const int n_lo = tnlo[tile], n_hi1 = tnlo[tile + 1];
        for (int n = n_lo + wid; n < n_hi1; n += 4) {
            float2 a = make_float2(0.f, 0.f);
            int i = off[n];
            const int e1 = off[n + 1];
            for (; i + 4 <= e1; i += 4) {
                int s0 = srcp[i], s1 = srcp[i + 1], s2 = srcp[i + 2], s3 = srcp[i + 3];
                unsigned int u0 = __builtin_nontemporal_load(&wmsg32[(size_t)(i    ) * 64 + lane]);
                unsigned int u1 = __builtin_nontemporal_load(&wmsg32[(size_t)(i + 1) * 64 + lane]);
                unsigned int u2 = __builtin_nontemporal_load(&wmsg32[(size_t)(i + 2) * 64 + lane]);
                unsigned int u3 = __builtin_nontemporal_load(&wmsg32[(size_t)(i + 3) * 64 + lane]);
                unsigned int v0 = y32[(size_t)s0 * 64 + lane];
                unsigned int v1 = y32[(size_t)s1 * 64 + lane];
                unsigned int v2 = y32[(size_t)s2 * 64 + lane];
                unsigned int v3 = y32[(size_t)s3 * 64 + lane];
                f16x2 m0 = *(const f16x2*)&u0, m1 = *(const f16x2*)&u1;
                f16x2 m2 = *(const f16x2*)&u2, m3 = *(const f16x2*)&u3;
                f16x2 q0 = *(const f16x2*)&v0, q1 = *(const f16x2*)&v1;
                f16x2 q2 = *(const f16x2*)&v2, q3 = *(const f16x2*)&v3;
                a.x = fmaf((float)m0[0], (float)q0[0], a.x); a.y = fmaf((float)m0[1], (float)q0[1], a.y);
                a.x = fmaf((float)m1[0], (float)q1[0], a.x); a.y = fmaf((float)m1[1], (float)q1[1], a.y);
                a.x = fmaf((float)m2[0], (float)q2[0], a.x); a.y = fmaf((float)m2[1], (float)q2[1], a.y);
                a.x = fmaf((float)m3[0], (float)q3[0], a.x); a.y = fmaf((float)m3[1], (float)q3[1], a.y);
            }
            for (; i < e1; i++) {
                unsigned int u = __builtin_nontemporal_load(&wmsg32[(size_t)i * 64 + lane]);
                unsigned int v = y32[(size_t)srcp[i] * 64 + lane];
                f16x2 mp = *(const f16x2*)&u;
                f16x2 qv = *(const f16x2*)&v;
                a.x = fmaf((float)mp[0], (float)qv[0], a.x);
                a.y = fmaf((float)mp[1], (float)qv[1], a.y);
            }
            f16x2 o; o[0] = (_Float16)a.x; o[1] = (_Float16)a.y;
            agg32[(size_t)n * 64 + lane] = *(const unsigned int*)&o;
        }
    }
}

// -------------------------------------------------------------------------
extern "C" void kernel_launch(void* const* d_in, const int* in_sizes, int n_in,
                              void* d_out, int out_size, void* d_ws, size_t ws_size,
                              hipStream_t stream) {
    const float* tt    = (const float*)d_in[0];
    const float* xx    = (const float*)d_in[1];
    const int*   ei    = (const int*)d_in[2];
    const float* elen  = (const float*)d_in[3];
    const float* eattr = (const float*)d_in[4];
    const float* em1w  = (const float*)d_in[5];
    const float* em1b  = (const float*)d_in[6];
    const float* em2w  = (const float*)d_in[7];
    const float* em2b  = (const float*)d_in[8];
    const float* c1m1w = (const float*)d_in[9];
    const float* c1m2w = (const float*)d_in[10];
    const float* c1m2b = (const float*)d_in[11];
    const float* c2m1w = (const float*)d_in[12];
    const float* c2m2w = (const float*)d_in[13];
    const float* c2m2b = (const float*)d_in[14];
    const float* tew   = (const float*)d_in[15];
    const float* teb   = (const float*)d_in[16];
    const float* linw  = (const float*)d_in[17];
    const float* linb  = (const float*)d_in[18];

    const int n  = in_sizes[0];
    const int E_ = in_sizes[2] / 2;
    const int ntiles = (E_ + ET - 1) / ET;
    const int gtiles = (n + 63) >> 6;
    const int nch = (n + SCH - 1) / SCH;
    float* out = (float*)d_out;

    // ws layout: fp16 node buffers (3 x NB halfs) then CSR ints + wmsg.
    const size_t NB = (size_t)n * NF;
    _Float16* B0h = (_Float16*)d_ws;   // y1 / y2 / x3   (fp16)
    _Float16* B1h = B0h + NB;          // agg            (fp16)
    _Float16* B2h = B1h + NB;          // emb/t/x_mid    (fp16)
    int* off  = (int*)(B2h + NB);      // n+1
    int* perm = off + (n + 1);         // E
    int* deg  = perm + E_;             // n
    int* cur  = deg + n;               // n
    int* srcp = cur + n;               // E
    int* tnlo = srcp + E_;             // ntiles+1
    int* csum = tnlo + ntiles + 1;     // nch
    int* coff = csum + nch;            // nch
    float* Cp = (float*)(coff + nch);  // E
    unsigned int* wmsg32 = (unsigned int*)(Cp + E_);   // E*64 u32

    // ---- CSR build (multi-block scan) + ownership table
    hipMemsetAsync(deg, 0, (size_t)2 * n * sizeof(int), stream);
    deg_kernel<<<(E_ + 255) / 256, 256, 0, stream>>>(ei, deg, E_);
    scan_chunk<<<nch, 256, 0, stream>>>(deg, csum, n);
    scan_csum_k<<<1, 1024, 0, stream>>>(csum, coff, nch, off, n, E_);
    scan_emit<<<nch, 256, 0, stream>>>(deg, coff, off, n);
    scatter_kernel<<<(E_ + 255) / 256, 256, 0, stream>>>(ei, elen, off, cur,
                                                         perm, srcp, Cp, E_);
    tilebnd_kernel<<<(ntiles + 256) / 256, 256, 0, stream>>>(off, tnlo, n, ntiles);

    // emb -> B2h ; t = swish_emb @ te_w + te_b -> B2h (in-place safe)
    emb_kernel<<<(n * 64 + 255) / 256, 256, 0, stream>>>(tt, B2h, n);
    mfma_gemm<3, 1, 1><<<gtiles, 256, 0, stream>>>(B2h, tew, teb, nullptr, B2h, n);

    // msg = Wf*C (conv-invariant) computed ONCE; WT=128-edge tiles
    wf_kernel<<<1280, 512, 0, stream>>>(eattr, em1w, em1b, em2w, em2b,
                                        perm, Cp, wmsg32, E_);

    // y1 = xx @ c1_m1w -> B0h   (A = f32 input)
    mfma_gemm<0, 0, 1><<<gtiles, 256, 0, stream>>>(xx, c1m1w, nullptr, nullptr, B0h, n);

    // conv1 -> B1h
    red_conv<<<4096, 256, 0, stream>>>((const unsigned int*)B0h, wmsg32, srcp,
                                       off, tnlo, (unsigned int*)B1h, ntiles);

    // x_mid = ssp(agg @ c1_m2w + b + t) -> B2h (extra==out elementwise-safe)
    mfma_gemm<2, 1, 1><<<gtiles, 256, 0, stream>>>(B1h, c1m2w, c1m2b, B2h, B2h, n);

    // y2 = x_mid @ c2_m1w -> B0h
    mfma_gemm<0, 1, 1><<<gtiles, 256, 0, stream>>>(B2h, c2m1w, nullptr, nullptr, B0h, n);

    // conv2 -> B1h
    red_conv<<<4096, 256, 0, stream>>>((const unsigned int*)B0h, wmsg32, srcp,
                                       off, tnlo, (unsigned int*)B1h, ntiles);

    // x3 = ssp(agg @ c2_m2w + b) -> B0h ; out = ssp(x3 @ lin_w + b) -> d_out (f32)
    mfma_gemm<1, 1, 1><<<gtiles, 256, 0, stream>>>(B1h, c2m2w, c2m2b, nullptr, B0h, n);
    mfma_gemm<1, 1, 0><<<gtiles, 256, 0, stream>>>(B0h, linw, linb, nullptr, out, n);
}